// Round 20
// baseline (261.063 us; speedup 1.0000x reference)
//
#include <hip/hip_runtime.h>

// ---------------------------------------------------------------------------
// Fused QEff MultiHeadDotProductAttention (GQA, non-causal), MI355X gfx950.
// B=2 S=2048 d=2048 H=16 Hk=4 D=128.  All inputs f32; compute in bf16 MFMA.
//
// Round 20: R18's certified structure (DMA identity staging, shared K+V in
// LDS), with 32 q-rows per wave (row-groups rg=0,1): each K/V fragment
// ds_read feeds TWO MFMAs, halving the per-CU DS-pipe load (the measured
// bottleneck: 16 waves x 32 b128 reads x ~12cy ~= 6144 cy/tile vs 620 MFMA).
// 4 waves/block (256 thr), 128 q-rows/block, grid 512 (2 blocks/CU).
// T14 reg->ds_write staging abandoned (R19: races unexplainably; R5 too).
// ---------------------------------------------------------------------------

typedef __attribute__((ext_vector_type(4))) float f32x4;
typedef __attribute__((ext_vector_type(8))) short s16x8;
typedef __attribute__((ext_vector_type(4))) short s16x4;

__device__ __forceinline__ short f2bf(float f) {
  unsigned u = __builtin_bit_cast(unsigned, f);
  u += 0x7fffu + ((u >> 16) & 1u);   // round-to-nearest-even
  return (short)(u >> 16);
}

__device__ __forceinline__ f32x4 mfma_bf16_16x16x32(s16x8 a, s16x8 b, f32x4 c) {
  asm("v_mfma_f32_16x16x32_bf16 %0, %1, %2, %0" : "+v"(c) : "v"(a), "v"(b));
  return c;
}

__device__ __forceinline__ void gload_lds16(const void* g, void* l) {
  __builtin_amdgcn_global_load_lds(
      (const __attribute__((address_space(1))) unsigned*)g,
      (__attribute__((address_space(3))) unsigned*)l, 16, 0, 0);
}

// ---- 1. elementwise cast f32 -> bf16, vectorized x4 ------------------------
__global__ void k_cast(const float* __restrict__ in, short* __restrict__ out, int n4) {
  int i = blockIdx.x * blockDim.x + threadIdx.x;
  int stride = gridDim.x * blockDim.x;
  const f32x4* in4 = (const f32x4*)in;
  s16x4* out4 = (s16x4*)out;
  for (; i < n4; i += stride) {
    f32x4 v = in4[i];
    s16x4 o;
    o.x = f2bf(v.x); o.y = f2bf(v.y); o.z = f2bf(v.z); o.w = f2bf(v.w);
    out4[i] = o;
  }
}

// ---- 2. transpose + cast: W[R][C] f32 -> Wt[C][R] bf16 ---------------------
__global__ void k_transpose_cast(const float* __restrict__ in, short* __restrict__ out,
                                 int R, int C) {
  __shared__ float t[32][33];
  int tx = threadIdx.x, ty = threadIdx.y;
  int c0 = blockIdx.x * 32, r0 = blockIdx.y * 32;
#pragma unroll
  for (int i = 0; i < 4; ++i)
    t[ty + 8 * i][tx] = in[(size_t)(r0 + ty + 8 * i) * C + (c0 + tx)];
  __syncthreads();
#pragma unroll
  for (int i = 0; i < 4; ++i)
    out[(size_t)(c0 + ty + 8 * i) * R + (r0 + tx)] = f2bf(t[tx][ty + 8 * i]);
}

// ---- 4. transpose V slice of XQKV into Vt[bh*128+dd][s] --------------------
__global__ void k_transpose_v(const short* __restrict__ XQKV, short* __restrict__ Vt) {
  __shared__ short t[32][33];
  int tx = threadIdx.x, ty = threadIdx.y;
  int s0 = blockIdx.x * 32, d0 = blockIdx.y * 32;
  int bh = blockIdx.z, b = bh >> 2, hk = bh & 3;
  const short* src = XQKV + (size_t)b * 2048 * 3072 + 2560 + hk * 128;
  short* dst = Vt + (size_t)bh * 128 * 2048;
#pragma unroll
  for (int i = 0; i < 4; ++i)
    t[ty + 8 * i][tx] = src[(size_t)(s0 + ty + 8 * i) * 3072 + (d0 + tx)];
  __syncthreads();
#pragma unroll
  for (int i = 0; i < 4; ++i)
    dst[(size_t)(d0 + ty + 8 * i) * 2048 + (s0 + tx)] = t[tx][ty + 8 * i];
}

// ---- 4b. repack K into fragment-major Kc (R14-exact) -----------------------
__global__ void k_prep_k(const short* __restrict__ XQKV, short* __restrict__ Kc) {
  int cid = blockIdx.x * 256 + threadIdx.x;   // 262144 total
  int l = cid & 63, ks = (cid >> 6) & 3, T = (cid >> 8) & 127, bh = cid >> 15;
  int ql = l & 15, g = l >> 4;
  int b = bh >> 2, hk = bh & 3;
  int s = T * 16 + ql;
  const s16x8 v = *(const s16x8*)(XQKV + ((size_t)b * 2048 + s) * 3072 + 2048 +
                                  hk * 128 + ks * 32 + g * 8);
  *(s16x8*)(Kc + (size_t)cid * 8) = v;
}

// ---- 4c. repack Vt into fragment-major Vc (R14-exact) ----------------------
__global__ void k_prep_v(const short* __restrict__ Vt, short* __restrict__ Vc) {
  int cid = blockIdx.x * 256 + threadIdx.x;   // 262144 total
  int l = cid & 63, dt = (cid >> 6) & 7, kvs = (cid >> 9) & 1;
  int U = (cid >> 10) & 31, bh = cid >> 15;
  int ql = l & 15, g = l >> 4;
  int dd = dt * 16 + ql, col = U * 64 + kvs * 32 + g * 8;
  const s16x8 v = *(const s16x8*)(Vt + (size_t)bh * 128 * 2048 + (size_t)dd * 2048 + col);
  *(s16x8*)(Vc + (size_t)cid * 8) = v;
}

// ---- 3./6. GEMM: C[M][N] = A[M][K] @ Bt[N][K]^T + bias  (R2-exact) ---------
template <int MODE>
__global__ __launch_bounds__(256) void k_gemm(const short* __restrict__ A,
                                              const short* __restrict__ Bt,
                                              const float* __restrict__ b0,
                                              const float* __restrict__ b1,
                                              const float* __restrict__ b2,
                                              void* __restrict__ Cout,
                                              int M, int N, int K) {
  __shared__ __align__(16) short lA[128 * 64];
  __shared__ __align__(16) short lB[128 * 64];
  const int tid = threadIdx.x;
  const int l = tid & 63, w = tid >> 6;
  const int ql = l & 15, g = l >> 4;
  const int wm = w >> 1, wn = w & 1;
  const int m0 = blockIdx.y * 128, n0 = blockIdx.x * 128;
  const int sr = l >> 3, sc = l & 7;

  f32x4 acc[4][4];
#pragma unroll
  for (int ii = 0; ii < 4; ++ii)
#pragma unroll
    for (int jj = 0; jj < 4; ++jj) acc[ii][jj] = (f32x4){0.f, 0.f, 0.f, 0.f};

  const int ktiles = K >> 6;
  for (int kt = 0; kt < ktiles; ++kt) {
    __syncthreads();
#pragma unroll
    for (int i = 0; i < 4; ++i) {
      int r = w * 32 + i * 8 + sr;
      int cg = sc ^ (r & 7);
      gload_lds16(A + (size_t)(m0 + r) * K + kt * 64 + cg * 8,
                  &lA[(w * 32 + i * 8) * 64]);
    }
#pragma unroll
    for (int i = 0; i < 4; ++i) {
      int r = w * 32 + i * 8 + sr;
      int cg = sc ^ (r & 7);
      gload_lds16(Bt + (size_t)(n0 + r) * K + kt * 64 + cg * 8,
                  &lB[(w * 32 + i * 8) * 64]);
    }
    __syncthreads();
#pragma unroll
    for (int ks = 0; ks < 2; ++ks) {
      s16x8 af[4], bf[4];
#pragma unroll
      for (int mi = 0; mi < 4; ++mi) {
        int r = wm * 64 + mi * 16 + ql;
        int ch = (ks * 4 + g) ^ (r & 7);
        af[mi] = *(const s16x8*)&lA[r * 64 + ch * 8];
      }
#pragma unroll
      for (int ni = 0; ni < 4; ++ni) {
        int r = wn * 64 + ni * 16 + ql;
        int ch = (ks * 4 + g) ^ (r & 7);
        bf[ni] = *(const s16x8*)&lB[r * 64 + ch * 8];
      }
#pragma unroll
      for (int mi = 0; mi < 4; ++mi)
#pragma unroll
        for (int ni = 0; ni < 4; ++ni)
          acc[mi][ni] = mfma_bf16_16x16x32(af[mi], bf[ni], acc[mi][ni]);
    }
  }

#pragma unroll
  for (int mi = 0; mi < 4; ++mi) {
#pragma unroll
    for (int ni = 0; ni < 4; ++ni) {
      int col = n0 + wn * 64 + ni * 16 + ql;
      int row0 = m0 + wm * 64 + mi * 16 + g * 4;
      float bias;
      if (MODE == 0)
        bias = (col < 2048) ? b0[col] : (col < 2560 ? b1[col - 2048] : b2[col - 2560]);
      else
        bias = b0[col];
      f32x4 v = acc[mi][ni];
      if (MODE == 0) {
        short* C = (short*)Cout;
#pragma unroll
        for (int j = 0; j < 4; ++j) C[(size_t)(row0 + j) * N + col] = f2bf(v[j] + bias);
      } else {
        float* C = (float*)Cout;
#pragma unroll
        for (int j = 0; j < 4; ++j) C[(size_t)(row0 + j) * N + col] = v[j] + bias;
      }
    }
  }
}

// ---- 5. flash attention (4 waves x 32 q-rows; shared DMA-staged K+V) -------
// grid = 512 linear blocks; LID&7 = (b,hk) group (XCD-local working set);
// j=LID>>3: h = hk*4 + (j>>4), q-block = j&15 (128 q-rows per block).
// Per tile: barrier -> stage 16KB K + 16KB V (identity DMA, 4+4 per wave) ->
// barrier -> compute with rg=0,1 row-groups (each kf/vf read feeds 2 MFMAs).
// LDS: lK 16K + lV 16K + P 4x[32][72] = 51200B -> 2 blocks/CU.
__global__ __launch_bounds__(256, 2) void k_attn(const short* __restrict__ XQKV,
                                                 const short* __restrict__ Kc,
                                                 const short* __restrict__ Vc,
                                                 short* __restrict__ Out) {
  __shared__ __align__(16) char smem[16384 + 16384 + 4 * 4608];
  short* lK = (short*)smem;              // 16 fragments x 512 shorts
  short* lV = (short*)(smem + 16384);    // 16 fragments x 512 shorts
  const int tid = threadIdx.x;
  const int l = tid & 63, w = tid >> 6;   // w in 0..3
  const int ql = l & 15, g = l >> 4;

  const int LID = blockIdx.x;
  const int grp = LID & 7;        // (b,hk) group -> XCD
  const int j = LID >> 3;         // 0..63
  const int b = grp >> 2, hk = grp & 3;
  const int h = hk * 4 + (j >> 4);
  const int bx = j & 15;
  const int bh = b * 4 + hk;

  const int q0 = bx * 128 + w * 32;
  const short* qp = XQKV + (size_t)b * 2048 * 3072 + h * 128;
  const short* kcb = Kc + (size_t)bh * 512 * 512;       // 512 fragments/bh
  const short* vcb = Vc + (size_t)bh * 512 * 512;
  short(*P)[72] = (short(*)[72])(smem + 32768 + w * 4608);  // [32][72] per wave
  short* OLb = (short*)(smem + w * 4608);  // epilogue only (reuses lK/lV, post-barrier)

  s16x8 qreg[2][4];
#pragma unroll
  for (int rg = 0; rg < 2; ++rg)
#pragma unroll
    for (int ks = 0; ks < 4; ++ks)
      qreg[rg][ks] =
          *(const s16x8*)(qp + (size_t)(q0 + rg * 16 + ql) * 3072 + ks * 32 + g * 8);

  float mo[2][4], ls[2][4];
#pragma unroll
  for (int rg = 0; rg < 2; ++rg)
#pragma unroll
    for (int jj = 0; jj < 4; ++jj) { mo[rg][jj] = -1e30f; ls[rg][jj] = 0.f; }
  f32x4 ot[2][8];
#pragma unroll
  for (int rg = 0; rg < 2; ++rg)
#pragma unroll
    for (int dt = 0; dt < 8; ++dt) ot[rg][dt] = (f32x4){0.f, 0.f, 0.f, 0.f};

  const float scale = 0.08838834764831845f;  // 1/sqrt(128)

  for (int kt = 0; kt < 32; ++kt) {
    __syncthreads();   // all waves done reading previous tile
    // ---- stage: identity copy, 16 K-segs + 16 V-segs of 1KB, 4+4 per wave --
#pragma unroll
    for (int i = 0; i < 4; ++i) {
      int s = w * 4 + i;
      gload_lds16(kcb + ((size_t)kt * 16 + s) * 512 + l * 8, (char*)lK + s * 1024);
      gload_lds16(vcb + ((size_t)kt * 16 + s) * 512 + l * 8, (char*)lV + s * 1024);
    }
    __syncthreads();   // staged tile visible (compiler drains vmcnt)

    // ---- QK^T: each kf read feeds both row-groups ----
    f32x4 st[2][4];
#pragma unroll
    for (int rg = 0; rg < 2; ++rg)
#pragma unroll
      for (int t = 0; t < 4; ++t) st[rg][t] = (f32x4){0.f, 0.f, 0.f, 0.f};
#pragma unroll
    for (int t = 0; t < 4; ++t)
#pragma unroll
      for (int ks = 0; ks < 4; ++ks) {
        s16x8 kf = *(const s16x8*)(lK + (t * 4 + ks) * 512 + l * 8);
        st[0][t] = mfma_bf16_16x16x32(qreg[0][ks], kf, st[0][t]);
        st[1][t] = mfma_bf16_16x16x32(qreg[1][ks], kf, st[1][t]);
      }

    // ---- online softmax (wave-parallel, 16-lane-group reduce), per rg ----
    float fac[2][4];
#pragma unroll
    for (int rg = 0; rg < 2; ++rg)
#pragma unroll
      for (int jj = 0; jj < 4; ++jj) {
#pragma unroll
        for (int t = 0; t < 4; ++t) st[rg][t][jj] *= scale;
        float mt = fmaxf(fmaxf(st[rg][0][jj], st[rg][1][jj]),
                         fmaxf(st[rg][2][jj], st[rg][3][jj]));
        mt = fmaxf(mt, __shfl_xor(mt, 1));
        mt = fmaxf(mt, __shfl_xor(mt, 2));
        mt = fmaxf(mt, __shfl_xor(mt, 4));
        mt = fmaxf(mt, __shfl_xor(mt, 8));
        float mn = fmaxf(mo[rg][jj], mt);
        fac[rg][jj] = __expf(mo[rg][jj] - mn);
        mo[rg][jj] = mn;
#pragma unroll
        for (int t = 0; t < 4; ++t) st[rg][t][jj] = __expf(st[rg][t][jj] - mn);
        float rs = st[rg][0][jj] + st[rg][1][jj] + st[rg][2][jj] + st[rg][3][jj];
        rs += __shfl_xor(rs, 1);
        rs += __shfl_xor(rs, 2);
        rs += __shfl_xor(rs, 4);
        rs += __shfl_xor(rs, 8);
        ls[rg][jj] = ls[rg][jj] * fac[rg][jj] + rs;
      }

    // ---- stage P to per-wave LDS (bf16); same-wave, in-order DS pipe ----
#pragma unroll
    for (int rg = 0; rg < 2; ++rg)
#pragma unroll
      for (int t = 0; t < 4; ++t)
#pragma unroll
        for (int jj = 0; jj < 4; ++jj)
          P[rg * 16 + g * 4 + jj][t * 16 + ql] = f2bf(st[rg][t][jj]);

    // ---- rescale Ot; factor for q = lane&15 via shfl, per rg ----
#pragma unroll
    for (int rg = 0; rg < 2; ++rg) {
      int j2 = ql & 3;
      float fv = (j2 == 0) ? fac[rg][0]
               : ((j2 == 1) ? fac[rg][1] : ((j2 == 2) ? fac[rg][2] : fac[rg][3]));
      float facq = __shfl(fv, ((ql >> 2) << 4) | ql);
#pragma unroll
      for (int dt = 0; dt < 8; ++dt) {
        ot[rg][dt][0] *= facq; ot[rg][dt][1] *= facq;
        ot[rg][dt][2] *= facq; ot[rg][dt][3] *= facq;
      }
    }

    // ---- PV: each vf read feeds both row-groups ----
    s16x8 pf00 = *(const s16x8*)&P[ql][0 * 32 + g * 8];
    s16x8 pf01 = *(const s16x8*)&P[ql][1 * 32 + g * 8];
    s16x8 pf10 = *(const s16x8*)&P[16 + ql][0 * 32 + g * 8];
    s16x8 pf11 = *(const s16x8*)&P[16 + ql][1 * 32 + g * 8];
#pragma unroll
    for (int dt = 0; dt < 8; ++dt) {
      s16x8 vf = *(const s16x8*)(lV + dt * 512 + l * 8);
      ot[0][dt] = mfma_bf16_16x16x32(vf, pf00, ot[0][dt]);
      ot[1][dt] = mfma_bf16_16x16x32(vf, pf10, ot[1][dt]);
    }
#pragma unroll
    for (int dt = 0; dt < 8; ++dt) {
      s16x8 vf = *(const s16x8*)(lV + (8 + dt) * 512 + l * 8);
      ot[0][dt] = mfma_bf16_16x16x32(vf, pf01, ot[0][dt]);
      ot[1][dt] = mfma_bf16_16x16x32(vf, pf11, ot[1][dt]);
    }
  }

  __syncthreads();  // all waves done with lK/lV/P before OLb overwrites them

  // ---- normalize + store per row-group (OLb per-wave, same-wave RAW) ----
#pragma unroll
  for (int rg = 0; rg < 2; ++rg) {
    float iv[4];
#pragma unroll
    for (int jj = 0; jj < 4; ++jj) iv[jj] = 1.f / ls[rg][jj];
    int j2 = ql & 3;
    float fv = (j2 == 0) ? iv[0] : ((j2 == 1) ? iv[1] : ((j2 == 2) ? iv[2] : iv[3]));
    float invq = __shfl(fv, ((ql >> 2) << 4) | ql);
#pragma unroll
    for (int dt = 0; dt < 8; ++dt)
#pragma unroll
      for (int jj = 0; jj < 4; ++jj)
        OLb[ql * 136 + dt * 16 + g * 4 + jj] = f2bf(ot[rg][dt][jj] * invq);
#pragma unroll
    for (int pass = 0; pass < 4; ++pass) {
      int r = pass * 4 + g;
      s16x8 o = *(const s16x8*)&OLb[r * 136 + ql * 8];
      *(s16x8*)(Out + (size_t)(b * 2048 + q0 + rg * 16 + r) * 2048 + h * 128 + ql * 8) = o;
    }
  }
}

// ---------------------------------------------------------------------------
extern "C" void kernel_launch(void* const* d_in, const int* in_sizes, int n_in,
                              void* d_out, int out_size, void* d_ws, size_t ws_size,
                              hipStream_t stream) {
  const float* x  = (const float*)d_in[0];
  const float* wq = (const float*)d_in[1];
  const float* bq = (const float*)d_in[2];
  const float* wk = (const float*)d_in[3];
  const float* bk = (const float*)d_in[4];
  const float* wv = (const float*)d_in[5];
  const float* bv = (const float*)d_in[6];
  const float* wo = (const float*)d_in[7];
  const float* bo = (const float*)d_in[8];
  float* out = (float*)d_out;

  char* ws = (char*)d_ws;
  short* Xb   = (short*)(ws);                        // 16 MB, also AttnOut
  short* Wqkv = (short*)(ws + (size_t)(16u << 20));  // 12 MB (dead after gemm<0>)
  short* Kc   = (short*)(ws + (size_t)(16u << 20));  // 4 MB, reuses Wqkv region
  short* Vc   = (short*)(ws + (size_t)(20u << 20));  // 4 MB, reuses Wqkv region
  short* WoT  = (short*)(ws + (size_t)(28u << 20));  // 8 MB
  short* XQKV = (short*)(ws + (size_t)(36u << 20));  // 24 MB
  short* Vt   = (short*)(ws + (size_t)(60u << 20));  // 4 MB

  dim3 tb(32, 8);

  k_cast<<<2048, 256, 0, stream>>>(x, Xb, 4096 * 2048 / 4);
  k_transpose_cast<<<dim3(64, 64), tb, 0, stream>>>(wq, Wqkv, 2048, 2048);
  k_transpose_cast<<<dim3(16, 64), tb, 0, stream>>>(wk, Wqkv + (size_t)2048 * 2048, 2048, 512);
  k_transpose_cast<<<dim3(16, 64), tb, 0, stream>>>(wv, Wqkv + (size_t)2560 * 2048, 2048, 512);
  k_transpose_cast<<<dim3(64, 64), tb, 0, stream>>>(wo, WoT, 2048, 2048);

  k_gemm<0><<<dim3(3072 / 128, 4096 / 128), 256, 0, stream>>>(
      Xb, Wqkv, bq, bk, bv, (void*)XQKV, 4096, 3072, 2048);

  k_transpose_v<<<dim3(64, 4, 8), tb, 0, stream>>>(XQKV, Vt);
  k_prep_k<<<1024, 256, 0, stream>>>(XQKV, Kc);   // overwrites dead Wqkv region
  k_prep_v<<<1024, 256, 0, stream>>>(Vt, Vc);

  k_attn<<<dim3(512), 256, 0, stream>>>(XQKV, Kc, Vc, Xb);

  k_gemm<1><<<dim3(2048 / 128, 4096 / 128), 256, 0, stream>>>(
      Xb, WoT, bo, bo, bo, (void*)out, 4096, 2048, 2048);
}

// Round 21
// 247.360 us; speedup vs baseline: 1.0554x; 1.0554x over previous
//
#include <hip/hip_runtime.h>

// ---------------------------------------------------------------------------
// Fused QEff MultiHeadDotProductAttention (GQA, non-causal), MI355X gfx950.
// B=2 S=2048 d=2048 H=16 Hk=4 D=128.  All inputs f32; compute in bf16 MFMA.
//
// Round 21: attention = R18-exact (best, 139.6us).  The three prep kernels
// (transpose_v / prep_k / prep_v) are FUSED into k_gemm<0>'s epilogue:
// K/V outputs are written directly in fragment-major Kc/Vc layout, Q to a
// packed Qb[4096][2048].  Same store count, ~32MB less traffic, 3 fewer
// launches.  Index algebra verified against the old prep kernels (bit-
// identical outputs).  R20 (32 rows/wave) regressed and is reverted.
//
// Workspace (60MB): Xb[0,16) Wqkv[16,28) WoT[28,36) Qb[36,52) Kc[52,56) Vc[56,60)
// ---------------------------------------------------------------------------

typedef __attribute__((ext_vector_type(4))) float f32x4;
typedef __attribute__((ext_vector_type(8))) short s16x8;
typedef __attribute__((ext_vector_type(4))) short s16x4;

__device__ __forceinline__ short f2bf(float f) {
  unsigned u = __builtin_bit_cast(unsigned, f);
  u += 0x7fffu + ((u >> 16) & 1u);   // round-to-nearest-even
  return (short)(u >> 16);
}

__device__ __forceinline__ f32x4 mfma_bf16_16x16x32(s16x8 a, s16x8 b, f32x4 c) {
  asm("v_mfma_f32_16x16x32_bf16 %0, %1, %2, %0" : "+v"(c) : "v"(a), "v"(b));
  return c;
}

__device__ __forceinline__ void gload_lds16(const void* g, void* l) {
  __builtin_amdgcn_global_load_lds(
      (const __attribute__((address_space(1))) unsigned*)g,
      (__attribute__((address_space(3))) unsigned*)l, 16, 0, 0);
}

// ---- 1. elementwise cast f32 -> bf16, vectorized x4 ------------------------
__global__ void k_cast(const float* __restrict__ in, short* __restrict__ out, int n4) {
  int i = blockIdx.x * blockDim.x + threadIdx.x;
  int stride = gridDim.x * blockDim.x;
  const f32x4* in4 = (const f32x4*)in;
  s16x4* out4 = (s16x4*)out;
  for (; i < n4; i += stride) {
    f32x4 v = in4[i];
    s16x4 o;
    o.x = f2bf(v.x); o.y = f2bf(v.y); o.z = f2bf(v.z); o.w = f2bf(v.w);
    out4[i] = o;
  }
}

// ---- 2. transpose + cast: W[R][C] f32 -> Wt[C][R] bf16 ---------------------
__global__ void k_transpose_cast(const float* __restrict__ in, short* __restrict__ out,
                                 int R, int C) {
  __shared__ float t[32][33];
  int tx = threadIdx.x, ty = threadIdx.y;
  int c0 = blockIdx.x * 32, r0 = blockIdx.y * 32;
#pragma unroll
  for (int i = 0; i < 4; ++i)
    t[ty + 8 * i][tx] = in[(size_t)(r0 + ty + 8 * i) * C + (c0 + tx)];
  __syncthreads();
#pragma unroll
  for (int i = 0; i < 4; ++i)
    out[(size_t)(c0 + ty + 8 * i) * R + (r0 + tx)] = f2bf(t[tx][ty + 8 * i]);
}

// ---- 3./6. GEMM: C[M][N] = A[M][K] @ Bt[N][K]^T + bias ---------------------
// MODE 0 (QKV): Q cols [0,2048) -> Qb[row][col] (packed, stride 2048);
//               K cols [2048,2560) -> Kc fragment-major;
//               V cols [2560,3072) -> Vc fragment-major.
// MODE 1: f32 out + single bias.
template <int MODE>
__global__ __launch_bounds__(256) void k_gemm(const short* __restrict__ A,
                                              const short* __restrict__ Bt,
                                              const float* __restrict__ b0,
                                              const float* __restrict__ b1,
                                              const float* __restrict__ b2,
                                              void* __restrict__ Cout,
                                              short* __restrict__ Kc,
                                              short* __restrict__ Vc,
                                              int M, int N, int K) {
  __shared__ __align__(16) short lA[128 * 64];
  __shared__ __align__(16) short lB[128 * 64];
  const int tid = threadIdx.x;
  const int l = tid & 63, w = tid >> 6;
  const int ql = l & 15, g = l >> 4;
  const int wm = w >> 1, wn = w & 1;
  const int m0 = blockIdx.y * 128, n0 = blockIdx.x * 128;
  const int sr = l >> 3, sc = l & 7;

  f32x4 acc[4][4];
#pragma unroll
  for (int ii = 0; ii < 4; ++ii)
#pragma unroll
    for (int jj = 0; jj < 4; ++jj) acc[ii][jj] = (f32x4){0.f, 0.f, 0.f, 0.f};

  const int ktiles = K >> 6;
  for (int kt = 0; kt < ktiles; ++kt) {
    __syncthreads();
#pragma unroll
    for (int i = 0; i < 4; ++i) {
      int r = w * 32 + i * 8 + sr;
      int cg = sc ^ (r & 7);
      gload_lds16(A + (size_t)(m0 + r) * K + kt * 64 + cg * 8,
                  &lA[(w * 32 + i * 8) * 64]);
    }
#pragma unroll
    for (int i = 0; i < 4; ++i) {
      int r = w * 32 + i * 8 + sr;
      int cg = sc ^ (r & 7);
      gload_lds16(Bt + (size_t)(n0 + r) * K + kt * 64 + cg * 8,
                  &lB[(w * 32 + i * 8) * 64]);
    }
    __syncthreads();
#pragma unroll
    for (int ks = 0; ks < 2; ++ks) {
      s16x8 af[4], bf[4];
#pragma unroll
      for (int mi = 0; mi < 4; ++mi) {
        int r = wm * 64 + mi * 16 + ql;
        int ch = (ks * 4 + g) ^ (r & 7);
        af[mi] = *(const s16x8*)&lA[r * 64 + ch * 8];
      }
#pragma unroll
      for (int ni = 0; ni < 4; ++ni) {
        int r = wn * 64 + ni * 16 + ql;
        int ch = (ks * 4 + g) ^ (r & 7);
        bf[ni] = *(const s16x8*)&lB[r * 64 + ch * 8];
      }
#pragma unroll
      for (int mi = 0; mi < 4; ++mi)
#pragma unroll
        for (int ni = 0; ni < 4; ++ni)
          acc[mi][ni] = mfma_bf16_16x16x32(af[mi], bf[ni], acc[mi][ni]);
    }
  }

#pragma unroll
  for (int mi = 0; mi < 4; ++mi) {
#pragma unroll
    for (int ni = 0; ni < 4; ++ni) {
      int col = n0 + wn * 64 + ni * 16 + ql;
      int row0 = m0 + wm * 64 + mi * 16 + g * 4;
      float bias;
      if (MODE == 0)
        bias = (col < 2048) ? b0[col] : (col < 2560 ? b1[col - 2048] : b2[col - 2560]);
      else
        bias = b0[col];
      f32x4 v = acc[mi][ni];
      if (MODE == 0) {
        if (col < 2048) {
          short* Qb = (short*)Cout;
#pragma unroll
          for (int j = 0; j < 4; ++j)
            Qb[(size_t)(row0 + j) * 2048 + col] = f2bf(v[j] + bias);
        } else if (col < 2560) {
          // K -> Kc fragment-major: idx = (bh*2^15 + T*2^8 + ks*2^6 + lane)*8 + pos
          int c = col - 2048, hk = c >> 7, d = c & 127;
          int ks2 = d >> 5, g2 = (d >> 3) & 3, pos = d & 7;
#pragma unroll
          for (int j = 0; j < 4; ++j) {
            int row = row0 + j, b2 = row >> 11, s = row & 2047;
            int T = s >> 4, lane = (s & 15) + 16 * g2;
            size_t idx = ((((size_t)(b2 * 4 + hk) * 128 + T) * 4 + ks2) * 64 + lane) * 8 + pos;
            Kc[idx] = f2bf(v[j] + bias);
          }
        } else {
          // V -> Vc fragment-major: idx = (bh*2^15 + U*2^10 + kvs*2^9 + dt*2^6 + lane)*8 + pos
          int c = col - 2560, hk = c >> 7, dd = c & 127;
          int dt2 = dd >> 4, ql2 = dd & 15;
#pragma unroll
          for (int j = 0; j < 4; ++j) {
            int row = row0 + j, b2 = row >> 11, s = row & 2047;
            int U = s >> 6, kvs = (s >> 5) & 1, g2 = (s >> 3) & 3, pos = s & 7;
            int lane = ql2 + 16 * g2;
            size_t idx = (((((size_t)(b2 * 4 + hk) * 32 + U) * 2 + kvs) * 8 + dt2) * 64 + lane) * 8 + pos;
            Vc[idx] = f2bf(v[j] + bias);
          }
        }
      } else {
        float* C = (float*)Cout;
#pragma unroll
        for (int j = 0; j < 4; ++j) C[(size_t)(row0 + j) * N + col] = v[j] + bias;
      }
    }
  }
}

// ---- 5. flash attention (R18-exact; Q from packed Qb) ----------------------
// grid = 512 linear blocks; LID&7 = (b,hk) group (XCD-local working set);
// j=LID>>3: h = hk*4 + (j>>4), q-block = j&15 (128 q-rows per block).
// Per tile: barrier -> stage 16KB K + 16KB V (identity DMA, 2+2 per wave) ->
// barrier -> compute.  LDS: lK 16K + lV 16K + P 8x2304 = 51200B.
__global__ __launch_bounds__(512, 4) void k_attn(const short* __restrict__ Qb,
                                                 const short* __restrict__ Kc,
                                                 const short* __restrict__ Vc,
                                                 short* __restrict__ Out) {
  __shared__ __align__(16) char smem[16384 + 16384 + 8 * 2304];
  short* lK = (short*)smem;              // 16 fragments x 512 shorts
  short* lV = (short*)(smem + 16384);    // 16 fragments x 512 shorts
  const int tid = threadIdx.x;
  const int l = tid & 63, w = tid >> 6;   // w in 0..7
  const int ql = l & 15, g = l >> 4;

  const int LID = blockIdx.x;
  const int grp = LID & 7;        // (b,hk) group -> XCD
  const int j = LID >> 3;         // 0..63
  const int b = grp >> 2, hk = grp & 3;
  const int h = hk * 4 + (j >> 4);
  const int bx = j & 15;
  const int bh = b * 4 + hk;

  const int q0 = bx * 128 + w * 16;
  const short* qp = Qb + (size_t)b * 2048 * 2048 + h * 128;
  const short* kcb = Kc + (size_t)bh * 512 * 512;       // 512 fragments/bh
  const short* vcb = Vc + (size_t)bh * 512 * 512;
  short(*P)[72] = (short(*)[72])(smem + 32768 + w * 2304);
  short* OLb = (short*)(smem + w * 4608);  // epilogue only (reuses lK/lV/P, post-barrier)

  s16x8 qreg[4];
#pragma unroll
  for (int ks = 0; ks < 4; ++ks)
    qreg[ks] = *(const s16x8*)(qp + (size_t)(q0 + ql) * 2048 + ks * 32 + g * 8);

  float mo[4], ls[4];
#pragma unroll
  for (int jj = 0; jj < 4; ++jj) { mo[jj] = -1e30f; ls[jj] = 0.f; }
  f32x4 ot[8];
#pragma unroll
  for (int dt = 0; dt < 8; ++dt) ot[dt] = (f32x4){0.f, 0.f, 0.f, 0.f};

  const float scale = 0.08838834764831845f;  // 1/sqrt(128)

  for (int kt = 0; kt < 32; ++kt) {
    __syncthreads();   // all waves done reading previous tile
    // ---- stage: identity copy, 16 K-segs + 16 V-segs of 1KB, 2+2 per wave --
#pragma unroll
    for (int i = 0; i < 2; ++i) {
      int s = w * 2 + i;
      gload_lds16(kcb + ((size_t)kt * 16 + s) * 512 + l * 8, (char*)lK + s * 1024);
      gload_lds16(vcb + ((size_t)kt * 16 + s) * 512 + l * 8, (char*)lV + s * 1024);
    }
    __syncthreads();   // staged tile visible (compiler drains vmcnt)

    // ---- QK^T: K fragments from LDS + 16 MFMAs ----
    s16x8 kf[16];
#pragma unroll
    for (int f = 0; f < 16; ++f)
      kf[f] = *(const s16x8*)(lK + f * 512 + l * 8);

    f32x4 st[4];
#pragma unroll
    for (int t = 0; t < 4; ++t) st[t] = (f32x4){0.f, 0.f, 0.f, 0.f};
#pragma unroll
    for (int t = 0; t < 4; ++t)
#pragma unroll
      for (int ks = 0; ks < 4; ++ks)
        st[t] = mfma_bf16_16x16x32(qreg[ks], kf[t * 4 + ks], st[t]);

    // ---- online softmax (wave-parallel, 16-lane-group reduce) ----
    float fac[4];
#pragma unroll
    for (int jj = 0; jj < 4; ++jj) {
#pragma unroll
      for (int t = 0; t < 4; ++t) st[t][jj] *= scale;
      float mt = fmaxf(fmaxf(st[0][jj], st[1][jj]), fmaxf(st[2][jj], st[3][jj]));
      mt = fmaxf(mt, __shfl_xor(mt, 1));
      mt = fmaxf(mt, __shfl_xor(mt, 2));
      mt = fmaxf(mt, __shfl_xor(mt, 4));
      mt = fmaxf(mt, __shfl_xor(mt, 8));
      float mn = fmaxf(mo[jj], mt);
      fac[jj] = __expf(mo[jj] - mn);
      mo[jj] = mn;
#pragma unroll
      for (int t = 0; t < 4; ++t) st[t][jj] = __expf(st[t][jj] - mn);
      float rs = st[0][jj] + st[1][jj] + st[2][jj] + st[3][jj];
      rs += __shfl_xor(rs, 1);
      rs += __shfl_xor(rs, 2);
      rs += __shfl_xor(rs, 4);
      rs += __shfl_xor(rs, 8);
      ls[jj] = ls[jj] * fac[jj] + rs;
    }

    // ---- stage P to per-wave LDS (bf16); same-wave, in-order DS pipe ----
#pragma unroll
    for (int t = 0; t < 4; ++t)
#pragma unroll
      for (int jj = 0; jj < 4; ++jj)
        P[g * 4 + jj][t * 16 + ql] = f2bf(st[t][jj]);

    // ---- rescale Ot accumulator; factor for q = lane&15 via shfl ----
    {
      int j2 = ql & 3;
      float fv = (j2 == 0) ? fac[0] : ((j2 == 1) ? fac[1] : ((j2 == 2) ? fac[2] : fac[3]));
      float facq = __shfl(fv, ((ql >> 2) << 4) | ql);
#pragma unroll
      for (int dt = 0; dt < 8; ++dt) {
        ot[dt][0] *= facq; ot[dt][1] *= facq; ot[dt][2] *= facq; ot[dt][3] *= facq;
      }
    }

    // ---- PV: V fragments from LDS + MFMAs ----
    s16x8 vf[16];
#pragma unroll
    for (int f = 0; f < 16; ++f)
      vf[f] = *(const s16x8*)(lV + f * 512 + l * 8);
    s16x8 pf0 = *(const s16x8*)&P[ql][0 * 32 + g * 8];
    s16x8 pf1 = *(const s16x8*)&P[ql][1 * 32 + g * 8];
#pragma unroll
    for (int dt = 0; dt < 8; ++dt)
      ot[dt] = mfma_bf16_16x16x32(vf[dt], pf0, ot[dt]);
#pragma unroll
    for (int dt = 0; dt < 8; ++dt)
      ot[dt] = mfma_bf16_16x16x32(vf[8 + dt], pf1, ot[dt]);
  }

  __syncthreads();  // all waves done with lK/lV/P before OLb overwrites them

  // ---- normalize, transpose through per-wave LDS (bf16), coalesced store ---
  float iv[4];
#pragma unroll
  for (int jj = 0; jj < 4; ++jj) iv[jj] = 1.f / ls[jj];
  int j2 = ql & 3;
  float fv = (j2 == 0) ? iv[0] : ((j2 == 1) ? iv[1] : ((j2 == 2) ? iv[2] : iv[3]));
  float invq = __shfl(fv, ((ql >> 2) << 4) | ql);
#pragma unroll
  for (int dt = 0; dt < 8; ++dt)
#pragma unroll
    for (int jj = 0; jj < 4; ++jj)
      OLb[ql * 136 + dt * 16 + g * 4 + jj] = f2bf(ot[dt][jj] * invq);
#pragma unroll
  for (int pass = 0; pass < 4; ++pass) {
    int r = pass * 4 + g;
    s16x8 o = *(const s16x8*)&OLb[r * 136 + ql * 8];
    *(s16x8*)(Out + (size_t)(b * 2048 + q0 + r) * 2048 + h * 128 + ql * 8) = o;
  }
}

// ---------------------------------------------------------------------------
extern "C" void kernel_launch(void* const* d_in, const int* in_sizes, int n_in,
                              void* d_out, int out_size, void* d_ws, size_t ws_size,
                              hipStream_t stream) {
  const float* x  = (const float*)d_in[0];
  const float* wq = (const float*)d_in[1];
  const float* bq = (const float*)d_in[2];
  const float* wk = (const float*)d_in[3];
  const float* bk = (const float*)d_in[4];
  const float* wv = (const float*)d_in[5];
  const float* bv = (const float*)d_in[6];
  const float* wo = (const float*)d_in[7];
  const float* bo = (const float*)d_in[8];
  float* out = (float*)d_out;

  char* ws = (char*)d_ws;
  short* Xb   = (short*)(ws);                        // 16 MB, also AttnOut
  short* Wqkv = (short*)(ws + (size_t)(16u << 20));  // 12 MB
  short* WoT  = (short*)(ws + (size_t)(28u << 20));  // 8 MB
  short* Qb   = (short*)(ws + (size_t)(36u << 20));  // 16 MB
  short* Kc   = (short*)(ws + (size_t)(52u << 20));  // 4 MB
  short* Vc   = (short*)(ws + (size_t)(56u << 20));  // 4 MB

  dim3 tb(32, 8);

  k_cast<<<2048, 256, 0, stream>>>(x, Xb, 4096 * 2048 / 4);
  k_transpose_cast<<<dim3(64, 64), tb, 0, stream>>>(wq, Wqkv, 2048, 2048);
  k_transpose_cast<<<dim3(16, 64), tb, 0, stream>>>(wk, Wqkv + (size_t)2048 * 2048, 2048, 512);
  k_transpose_cast<<<dim3(16, 64), tb, 0, stream>>>(wv, Wqkv + (size_t)2560 * 2048, 2048, 512);
  k_transpose_cast<<<dim3(64, 64), tb, 0, stream>>>(wo, WoT, 2048, 2048);

  // QKV GEMM with fused layout epilogue: Q->Qb, K->Kc, V->Vc
  k_gemm<0><<<dim3(3072 / 128, 4096 / 128), 256, 0, stream>>>(
      Xb, Wqkv, bq, bk, bv, (void*)Qb, Kc, Vc, 4096, 3072, 2048);

  k_attn<<<dim3(512), 512, 0, stream>>>(Qb, Kc, Vc, Xb);

  k_gemm<1><<<dim3(2048 / 128, 4096 / 128), 256, 0, stream>>>(
      Xb, WoT, bo, bo, bo, (void*)out, nullptr, nullptr, 4096, 2048, 2048);
}

// Round 22
// 242.087 us; speedup vs baseline: 1.0784x; 1.0218x over previous
//
#include <hip/hip_runtime.h>

// ---------------------------------------------------------------------------
// Fused QEff MultiHeadDotProductAttention (GQA, non-causal), MI355X gfx950.
// B=2 S=2048 d=2048 H=16 Hk=4 D=128.  All inputs f32; compute in bf16 MFMA.
//
// Round 22: R21 + (a) V double-buffered one-tile-ahead prefetch with counted
// vmcnt (only K's 16KB DMA remains exposed per tile; V lands under the
// previous tile's compute).  LDS 51.2 -> 66KB, still 2 blocks/CU (grid=512).
// Per-iteration: syncthreads (drains V(kt), landed) -> issue K(kt) ->
// issue V(kt+1) -> s_waitcnt vmcnt(2) -> raw s_barrier -> compute.
// (b) the 4 weight-transpose launches merged into one z-indexed kernel.
// ---------------------------------------------------------------------------

typedef __attribute__((ext_vector_type(4))) float f32x4;
typedef __attribute__((ext_vector_type(8))) short s16x8;
typedef __attribute__((ext_vector_type(4))) short s16x4;

__device__ __forceinline__ short f2bf(float f) {
  unsigned u = __builtin_bit_cast(unsigned, f);
  u += 0x7fffu + ((u >> 16) & 1u);   // round-to-nearest-even
  return (short)(u >> 16);
}

__device__ __forceinline__ f32x4 mfma_bf16_16x16x32(s16x8 a, s16x8 b, f32x4 c) {
  asm("v_mfma_f32_16x16x32_bf16 %0, %1, %2, %0" : "+v"(c) : "v"(a), "v"(b));
  return c;
}

__device__ __forceinline__ void gload_lds16(const void* g, void* l) {
  __builtin_amdgcn_global_load_lds(
      (const __attribute__((address_space(1))) unsigned*)g,
      (__attribute__((address_space(3))) unsigned*)l, 16, 0, 0);
}

// ---- 1. elementwise cast f32 -> bf16, vectorized x4 ------------------------
__global__ void k_cast(const float* __restrict__ in, short* __restrict__ out, int n4) {
  int i = blockIdx.x * blockDim.x + threadIdx.x;
  int stride = gridDim.x * blockDim.x;
  const f32x4* in4 = (const f32x4*)in;
  s16x4* out4 = (s16x4*)out;
  for (; i < n4; i += stride) {
    f32x4 v = in4[i];
    s16x4 o;
    o.x = f2bf(v.x); o.y = f2bf(v.y); o.z = f2bf(v.z); o.w = f2bf(v.w);
    out4[i] = o;
  }
}

// ---- 2. merged transpose + cast for all four weights -----------------------
// z=0: wq[2048][2048] -> Wqkv[0..);  z=1: wk -> Wqkv+2048*2048;
// z=2: wv -> Wqkv+2560*2048;         z=3: wo -> WoT.
__global__ void k_transpose_cast_all(const float* __restrict__ wq,
                                     const float* __restrict__ wk,
                                     const float* __restrict__ wv,
                                     const float* __restrict__ wo,
                                     short* __restrict__ Wqkv,
                                     short* __restrict__ WoT) {
  __shared__ float t[32][33];
  const int which = blockIdx.z;
  const float* in;
  short* out;
  int C;
  if (which == 0)      { in = wq; out = Wqkv;                          C = 2048; }
  else if (which == 1) { in = wk; out = Wqkv + (size_t)2048 * 2048;    C = 512;  }
  else if (which == 2) { in = wv; out = Wqkv + (size_t)2560 * 2048;    C = 512;  }
  else                 { in = wo; out = WoT;                           C = 2048; }
  const int R = 2048;
  int c0 = blockIdx.x * 32, r0 = blockIdx.y * 32;
  if (c0 >= C) return;
  int tx = threadIdx.x, ty = threadIdx.y;
#pragma unroll
  for (int i = 0; i < 4; ++i)
    t[ty + 8 * i][tx] = in[(size_t)(r0 + ty + 8 * i) * C + (c0 + tx)];
  __syncthreads();
#pragma unroll
  for (int i = 0; i < 4; ++i)
    out[(size_t)(c0 + ty + 8 * i) * R + (r0 + tx)] = f2bf(t[tx][ty + 8 * i]);
}

// ---- 3./6. GEMM: C[M][N] = A[M][K] @ Bt[N][K]^T + bias  (R21-exact) --------
template <int MODE>
__global__ __launch_bounds__(256) void k_gemm(const short* __restrict__ A,
                                              const short* __restrict__ Bt,
                                              const float* __restrict__ b0,
                                              const float* __restrict__ b1,
                                              const float* __restrict__ b2,
                                              void* __restrict__ Cout,
                                              short* __restrict__ Kc,
                                              short* __restrict__ Vc,
                                              int M, int N, int K) {
  __shared__ __align__(16) short lA[128 * 64];
  __shared__ __align__(16) short lB[128 * 64];
  const int tid = threadIdx.x;
  const int l = tid & 63, w = tid >> 6;
  const int ql = l & 15, g = l >> 4;
  const int wm = w >> 1, wn = w & 1;
  const int m0 = blockIdx.y * 128, n0 = blockIdx.x * 128;
  const int sr = l >> 3, sc = l & 7;

  f32x4 acc[4][4];
#pragma unroll
  for (int ii = 0; ii < 4; ++ii)
#pragma unroll
    for (int jj = 0; jj < 4; ++jj) acc[ii][jj] = (f32x4){0.f, 0.f, 0.f, 0.f};

  const int ktiles = K >> 6;
  for (int kt = 0; kt < ktiles; ++kt) {
    __syncthreads();
#pragma unroll
    for (int i = 0; i < 4; ++i) {
      int r = w * 32 + i * 8 + sr;
      int cg = sc ^ (r & 7);
      gload_lds16(A + (size_t)(m0 + r) * K + kt * 64 + cg * 8,
                  &lA[(w * 32 + i * 8) * 64]);
    }
#pragma unroll
    for (int i = 0; i < 4; ++i) {
      int r = w * 32 + i * 8 + sr;
      int cg = sc ^ (r & 7);
      gload_lds16(Bt + (size_t)(n0 + r) * K + kt * 64 + cg * 8,
                  &lB[(w * 32 + i * 8) * 64]);
    }
    __syncthreads();
#pragma unroll
    for (int ks = 0; ks < 2; ++ks) {
      s16x8 af[4], bf[4];
#pragma unroll
      for (int mi = 0; mi < 4; ++mi) {
        int r = wm * 64 + mi * 16 + ql;
        int ch = (ks * 4 + g) ^ (r & 7);
        af[mi] = *(const s16x8*)&lA[r * 64 + ch * 8];
      }
#pragma unroll
      for (int ni = 0; ni < 4; ++ni) {
        int r = wn * 64 + ni * 16 + ql;
        int ch = (ks * 4 + g) ^ (r & 7);
        bf[ni] = *(const s16x8*)&lB[r * 64 + ch * 8];
      }
#pragma unroll
      for (int mi = 0; mi < 4; ++mi)
#pragma unroll
        for (int ni = 0; ni < 4; ++ni)
          acc[mi][ni] = mfma_bf16_16x16x32(af[mi], bf[ni], acc[mi][ni]);
    }
  }

#pragma unroll
  for (int mi = 0; mi < 4; ++mi) {
#pragma unroll
    for (int ni = 0; ni < 4; ++ni) {
      int col = n0 + wn * 64 + ni * 16 + ql;
      int row0 = m0 + wm * 64 + mi * 16 + g * 4;
      float bias;
      if (MODE == 0)
        bias = (col < 2048) ? b0[col] : (col < 2560 ? b1[col - 2048] : b2[col - 2560]);
      else
        bias = b0[col];
      f32x4 v = acc[mi][ni];
      if (MODE == 0) {
        if (col < 2048) {
          short* Qb = (short*)Cout;
#pragma unroll
          for (int j = 0; j < 4; ++j)
            Qb[(size_t)(row0 + j) * 2048 + col] = f2bf(v[j] + bias);
        } else if (col < 2560) {
          int c = col - 2048, hk = c >> 7, d = c & 127;
          int ks2 = d >> 5, g2 = (d >> 3) & 3, pos = d & 7;
#pragma unroll
          for (int j = 0; j < 4; ++j) {
            int row = row0 + j, b2 = row >> 11, s = row & 2047;
            int T = s >> 4, lane = (s & 15) + 16 * g2;
            size_t idx = ((((size_t)(b2 * 4 + hk) * 128 + T) * 4 + ks2) * 64 + lane) * 8 + pos;
            Kc[idx] = f2bf(v[j] + bias);
          }
        } else {
          int c = col - 2560, hk = c >> 7, dd = c & 127;
          int dt2 = dd >> 4, ql2 = dd & 15;
#pragma unroll
          for (int j = 0; j < 4; ++j) {
            int row = row0 + j, b2 = row >> 11, s = row & 2047;
            int U = s >> 6, kvs = (s >> 5) & 1, g2 = (s >> 3) & 3, pos = s & 7;
            int lane = ql2 + 16 * g2;
            size_t idx = (((((size_t)(b2 * 4 + hk) * 32 + U) * 2 + kvs) * 8 + dt2) * 64 + lane) * 8 + pos;
            Vc[idx] = f2bf(v[j] + bias);
          }
        }
      } else {
        float* C = (float*)Cout;
#pragma unroll
        for (int j = 0; j < 4; ++j) C[(size_t)(row0 + j) * N + col] = v[j] + bias;
      }
    }
  }
}

// ---- 5. flash attention (8 waves; K single-buffer, V dbuf 1-ahead) ---------
// grid = 512 linear blocks; LID&7 = (b,hk) group (XCD-local working set).
// Per tile kt: __syncthreads (prev compute done; drains V(kt), which landed
// under prev compute) -> issue K(kt) DMA -> issue V(kt+1) DMA into vb^1 ->
// s_waitcnt vmcnt(2) (K done, V(kt+1) in flight) -> raw s_barrier -> compute.
// LDS: lK 16K + vb[2] 32K + P 8x2304 = 67584B -> 2 blocks/CU.
__global__ __launch_bounds__(512, 4) void k_attn(const short* __restrict__ Qb,
                                                 const short* __restrict__ Kc,
                                                 const short* __restrict__ Vc,
                                                 short* __restrict__ Out) {
  __shared__ __align__(16) char smem[16384 + 32768 + 8 * 2304];
  short* lK = (short*)smem;                      // 16 fragments x 512 shorts
  const int tid = threadIdx.x;
  const int l = tid & 63, w = tid >> 6;   // w in 0..7
  const int ql = l & 15, g = l >> 4;

  const int LID = blockIdx.x;
  const int grp = LID & 7;        // (b,hk) group -> XCD
  const int j = LID >> 3;         // 0..63
  const int b = grp >> 2, hk = grp & 3;
  const int h = hk * 4 + (j >> 4);
  const int bx = j & 15;
  const int bh = b * 4 + hk;

  const int q0 = bx * 128 + w * 16;
  const short* qp = Qb + (size_t)b * 2048 * 2048 + h * 128;
  const short* kcb = Kc + (size_t)bh * 512 * 512;       // 512 fragments/bh
  const short* vcb = Vc + (size_t)bh * 512 * 512;
  short(*P)[72] = (short(*)[72])(smem + 49152 + w * 2304);
  short* OLb = (short*)(smem + w * 4608);  // epilogue only (post-barrier reuse)

  s16x8 qreg[4];
#pragma unroll
  for (int ks = 0; ks < 4; ++ks)
    qreg[ks] = *(const s16x8*)(qp + (size_t)(q0 + ql) * 2048 + ks * 32 + g * 8);

  float mo[4], ls[4];
#pragma unroll
  for (int jj = 0; jj < 4; ++jj) { mo[jj] = -1e30f; ls[jj] = 0.f; }
  f32x4 ot[8];
#pragma unroll
  for (int dt = 0; dt < 8; ++dt) ot[dt] = (f32x4){0.f, 0.f, 0.f, 0.f};

  const float scale = 0.08838834764831845f;  // 1/sqrt(128)

  // ---- prologue: prefetch V(0) into vb0 (drained by kt=0's syncthreads) ----
#pragma unroll
  for (int i = 0; i < 2; ++i) {
    int s = w * 2 + i;
    gload_lds16(vcb + (size_t)s * 512 + l * 8, smem + 16384 + s * 1024);
  }

  for (int kt = 0; kt < 32; ++kt) {
    __syncthreads();   // prev compute done; drains outstanding V(kt) (landed)
    // ---- issue K(kt) then V(kt+1); exactly 4 VMEM ops per wave ----
#pragma unroll
    for (int i = 0; i < 2; ++i) {
      int s = w * 2 + i;
      gload_lds16(kcb + ((size_t)kt * 16 + s) * 512 + l * 8, (char*)lK + s * 1024);
    }
    if (kt < 31) {
#pragma unroll
      for (int i = 0; i < 2; ++i) {
        int s = w * 2 + i;
        gload_lds16(vcb + ((size_t)(kt + 1) * 16 + s) * 512 + l * 8,
                    smem + 16384 + ((kt + 1) & 1) * 16384 + s * 1024);
      }
      asm volatile("s_waitcnt vmcnt(2)" ::: "memory");  // K done; V(kt+1) flies
    } else {
      asm volatile("s_waitcnt vmcnt(0)" ::: "memory");  // last tile: drain all
    }
    __builtin_amdgcn_sched_barrier(0);
    __builtin_amdgcn_s_barrier();   // publish lK(kt) + vb[kt&1] to all waves
    __builtin_amdgcn_sched_barrier(0);
    const short* lV = (const short*)(smem + 16384 + (kt & 1) * 16384);

    // ---- QK^T: K fragments from LDS + 16 MFMAs ----
    s16x8 kf[16];
#pragma unroll
    for (int f = 0; f < 16; ++f)
      kf[f] = *(const s16x8*)(lK + f * 512 + l * 8);

    f32x4 st[4];
#pragma unroll
    for (int t = 0; t < 4; ++t) st[t] = (f32x4){0.f, 0.f, 0.f, 0.f};
#pragma unroll
    for (int t = 0; t < 4; ++t)
#pragma unroll
      for (int ks = 0; ks < 4; ++ks)
        st[t] = mfma_bf16_16x16x32(qreg[ks], kf[t * 4 + ks], st[t]);

    // ---- online softmax (wave-parallel, 16-lane-group reduce) ----
    float fac[4];
#pragma unroll
    for (int jj = 0; jj < 4; ++jj) {
#pragma unroll
      for (int t = 0; t < 4; ++t) st[t][jj] *= scale;
      float mt = fmaxf(fmaxf(st[0][jj], st[1][jj]), fmaxf(st[2][jj], st[3][jj]));
      mt = fmaxf(mt, __shfl_xor(mt, 1));
      mt = fmaxf(mt, __shfl_xor(mt, 2));
      mt = fmaxf(mt, __shfl_xor(mt, 4));
      mt = fmaxf(mt, __shfl_xor(mt, 8));
      float mn = fmaxf(mo[jj], mt);
      fac[jj] = __expf(mo[jj] - mn);
      mo[jj] = mn;
#pragma unroll
      for (int t = 0; t < 4; ++t) st[t][jj] = __expf(st[t][jj] - mn);
      float rs = st[0][jj] + st[1][jj] + st[2][jj] + st[3][jj];
      rs += __shfl_xor(rs, 1);
      rs += __shfl_xor(rs, 2);
      rs += __shfl_xor(rs, 4);
      rs += __shfl_xor(rs, 8);
      ls[jj] = ls[jj] * fac[jj] + rs;
    }

    // ---- stage P to per-wave LDS (bf16); same-wave, in-order DS pipe ----
#pragma unroll
    for (int t = 0; t < 4; ++t)
#pragma unroll
      for (int jj = 0; jj < 4; ++jj)
        P[g * 4 + jj][t * 16 + ql] = f2bf(st[t][jj]);

    // ---- rescale Ot accumulator; factor for q = lane&15 via shfl ----
    {
      int j2 = ql & 3;
      float fv = (j2 == 0) ? fac[0] : ((j2 == 1) ? fac[1] : ((j2 == 2) ? fac[2] : fac[3]));
      float facq = __shfl(fv, ((ql >> 2) << 4) | ql);
#pragma unroll
      for (int dt = 0; dt < 8; ++dt) {
        ot[dt][0] *= facq; ot[dt][1] *= facq; ot[dt][2] *= facq; ot[dt][3] *= facq;
      }
    }

    // ---- PV: V fragments from LDS + MFMAs ----
    s16x8 vf[16];
#pragma unroll
    for (int f = 0; f < 16; ++f)
      vf[f] = *(const s16x8*)(lV + f * 512 + l * 8);
    s16x8 pf0 = *(const s16x8*)&P[ql][0 * 32 + g * 8];
    s16x8 pf1 = *(const s16x8*)&P[ql][1 * 32 + g * 8];
#pragma unroll
    for (int dt = 0; dt < 8; ++dt)
      ot[dt] = mfma_bf16_16x16x32(vf[dt], pf0, ot[dt]);
#pragma unroll
    for (int dt = 0; dt < 8; ++dt)
      ot[dt] = mfma_bf16_16x16x32(vf[8 + dt], pf1, ot[dt]);
  }

  __syncthreads();  // all waves done with lK/vb/P before OLb overwrites them

  // ---- normalize, transpose through per-wave LDS (bf16), coalesced store ---
  float iv[4];
#pragma unroll
  for (int jj = 0; jj < 4; ++jj) iv[jj] = 1.f / ls[jj];
  int j2 = ql & 3;
  float fv = (j2 == 0) ? iv[0] : ((j2 == 1) ? iv[1] : ((j2 == 2) ? iv[2] : iv[3]));
  float invq = __shfl(fv, ((ql >> 2) << 4) | ql);
#pragma unroll
  for (int dt = 0; dt < 8; ++dt)
#pragma unroll
    for (int jj = 0; jj < 4; ++jj)
      OLb[ql * 136 + dt * 16 + g * 4 + jj] = f2bf(ot[dt][jj] * invq);
#pragma unroll
  for (int pass = 0; pass < 4; ++pass) {
    int r = pass * 4 + g;
    s16x8 o = *(const s16x8*)&OLb[r * 136 + ql * 8];
    *(s16x8*)(Out + (size_t)(b * 2048 + q0 + r) * 2048 + h * 128 + ql * 8) = o;
  }
}

// ---------------------------------------------------------------------------
extern "C" void kernel_launch(void* const* d_in, const int* in_sizes, int n_in,
                              void* d_out, int out_size, void* d_ws, size_t ws_size,
                              hipStream_t stream) {
  const float* x  = (const float*)d_in[0];
  const float* wq = (const float*)d_in[1];
  const float* bq = (const float*)d_in[2];
  const float* wk = (const float*)d_in[3];
  const float* bk = (const float*)d_in[4];
  const float* wv = (const float*)d_in[5];
  const float* bv = (const float*)d_in[6];
  const float* wo = (const float*)d_in[7];
  const float* bo = (const float*)d_in[8];
  float* out = (float*)d_out;

  char* ws = (char*)d_ws;
  short* Xb   = (short*)(ws);                        // 16 MB, also AttnOut
  short* Wqkv = (short*)(ws + (size_t)(16u << 20));  // 12 MB
  short* WoT  = (short*)(ws + (size_t)(28u << 20));  // 8 MB
  short* Qb   = (short*)(ws + (size_t)(36u << 20));  // 16 MB
  short* Kc   = (short*)(ws + (size_t)(52u << 20));  // 4 MB
  short* Vc   = (short*)(ws + (size_t)(56u << 20));  // 4 MB

  k_cast<<<2048, 256, 0, stream>>>(x, Xb, 4096 * 2048 / 4);
  k_transpose_cast_all<<<dim3(64, 64, 4), dim3(32, 8), 0, stream>>>(
      wq, wk, wv, wo, Wqkv, WoT);

  // QKV GEMM with fused layout epilogue: Q->Qb, K->Kc, V->Vc
  k_gemm<0><<<dim3(3072 / 128, 4096 / 128), 256, 0, stream>>>(
      Xb, Wqkv, bq, bk, bv, (void*)Qb, Kc, Vc, 4096, 3072, 2048);

  k_attn<<<dim3(512), 512, 0, stream>>>(Qb, Kc, Vc, Xb);

  k_gemm<1><<<dim3(2048 / 128, 4096 / 128), 256, 0, stream>>>(
      Xb, WoT, bo, bo, bo, (void*)out, nullptr, nullptr, 4096, 2048, 2048);
}